// Round 10
// baseline (139.426 us; speedup 1.0000x reference)
//
#include <hip/hip_runtime.h>
#include <cstdint>

#define NB 8
#define TS 2048
#define NE 1024
#define HD 64
#define MTOT (NB*TS)

typedef float     f4  __attribute__((ext_vector_type(4)));
typedef short     s8v __attribute__((ext_vector_type(8)));
typedef short     s4v __attribute__((ext_vector_type(4)));
typedef int       i4v __attribute__((ext_vector_type(4)));
typedef _Float16  h8  __attribute__((ext_vector_type(8)));

__device__ __forceinline__ short f2bf(float f) {  // RNE
  union { float f; uint32_t u; } x; x.f = f;
  return (short)((x.u + 0x7FFFu + ((x.u >> 16) & 1u)) >> 16);
}

__device__ __forceinline__ int pack2(float lo, float hi) {
  union { float f; uint32_t u; } a, b; a.f = lo; b.f = hi;
  return (int)__builtin_amdgcn_perm(b.u + 0x8000u, a.u + 0x8000u, 0x07060302u);
}

// async global->LDS DMA, 16B/lane; lptr wave-uniform, lane i -> lptr + i*16
__device__ __forceinline__ void gl2lds(const void* gptr, void* lptr) {
  auto g = (const __attribute__((address_space(1))) uint32_t*)gptr;
  auto l = (__attribute__((address_space(3))) uint32_t*)lptr;
  __builtin_amdgcn_global_load_lds(g, l, 16, 0, 0);
}

// barrier keeping the N newest vmem ops (per wave) in flight
template <int N>
__device__ __forceinline__ void wait_barrier() {
  asm volatile("s_waitcnt vmcnt(%0) lgkmcnt(0)" :: "n"(N) : "memory");
  __builtin_amdgcn_s_barrier();
}

// ---- kernel 0: W fp32 -> bf16 (q-scale folded). wb [192][1024]: 0-63 q, 64-127 k, 128-191 v
__global__ __launch_bounds__(256) void wconv_kernel(
    const float* __restrict__ Wk, const float* __restrict__ Wq, const float* __restrict__ Wv,
    short* __restrict__ wb)
{
  const int idx = (blockIdx.x * 256 + threadIdx.x) * 4;
  const int p = idx >> 16;
  const int off = idx & 65535;
  const float* W = (p == 0) ? Wq : (p == 1) ? Wk : Wv;
  const float s = (p == 0) ? 0.18033688011112042f : 1.0f; // (1/8)*log2(e)
  const float4 v = *(const float4*)&W[off];
  s4v h; h[0] = f2bf(v.x*s); h[1] = f2bf(v.y*s); h[2] = f2bf(v.z*s); h[3] = f2bf(v.w*s);
  *(s4v*)&wb[idx] = h;
}

// ---- kernel 1: fused qkv projection. grid 512 x 256 thr, tile 32 rows x 192 cols,
// wave = 16 rows x 96 cols. K-chunks of 32 (32 iters). Xs 8-buf fp32 (4-ahead),
// Ws 4-buf bf16 (2-ahead) = 80 KB -> 2 blocks/CU. Steady wait<5>: X stays 2-3 deep in flight.
__global__ __launch_bounds__(256) void proj_kernel(
    const float* __restrict__ x, const short* __restrict__ wb,
    short* __restrict__ qo, short* __restrict__ ko, _Float16* __restrict__ vo)
{
  __shared__ __align__(16) char smem[81920];
  float (*Xs)[32][32] = (float (*)[32][32])smem;          // [8][32][32] f32 = 32 KB
  short (*Ws)[192][32] = (short (*)[192][32])(smem + 32768); // [4][192][32] bf16 = 48 KB

  const int tid = threadIdx.x;
  const int wv = tid >> 6, lane = tid & 63, n = lane & 15, quad = lane >> 4;
  const int mg = wv & 1, cg = wv >> 1;
  const int r0 = blockIdx.x * 32;

  // X DMA: chunk = 32 rows x 32 f32 (4 KB) = 1 instr/wave. lane -> row wv*8+(lane>>3), slot lane&7.
  auto dmaX = [&](int c) {
    const int row = wv * 8 + (lane >> 3);
    const int s = lane & 7;
    const int gs = (s + row) & 7;                         // slot swizzle (rows 128B apart)
    gl2lds(&x[(size_t)(r0 + row) * NE + c * 32 + gs * 4], &Xs[c & 7][wv * 8][0]);
  };
  // W DMA: chunk = 192 cols x 32 bf16 (12 KB) = 3 instr/wave. lane -> col C0+(lane>>2), slot lane&3.
  auto dmaW = [&](int c) {
#pragma unroll
    for (int u = 0; u < 3; ++u) {
      const int C0 = wv * 48 + u * 16;
      const int col = C0 + (lane >> 2);
      const int s = lane & 3;
      const int gs = (s + col + (col >> 2)) & 3;          // +col>>2 kills 4-apart bank conflicts
      gl2lds(&wb[(size_t)col * NE + c * 32 + gs * 8], &Ws[c & 3][C0][0]);
    }
  };

  const f4 fz = {0.f, 0.f, 0.f, 0.f};
  f4 acc[6] = {fz, fz, fz, fz, fz, fz};

  auto compute = [&](int t) {
    const int bx = t & 7, bw = t & 3;
    const int row = mg * 16 + n;
    const float* pr = &Xs[bx][row][0];
    const int u0 = quad * 2;
    const f4 f0 = *(const f4*)(pr + (((u0    ) - row) & 7) * 4);
    const f4 f1 = *(const f4*)(pr + (((u0 + 1) - row) & 7) * 4);
    i4v ai;
    ai[0] = pack2(f0[0], f0[1]); ai[1] = pack2(f0[2], f0[3]);
    ai[2] = pack2(f1[0], f1[1]); ai[3] = pack2(f1[2], f1[3]);
    const s8v af = __builtin_bit_cast(s8v, ai);
#pragma unroll
    for (int nf = 0; nf < 6; ++nf) {
      const int col = cg * 96 + nf * 16 + n;
      const s8v bf = *(const s8v*)&Ws[bw][col][((quad - col - (col >> 2)) & 3) * 8];
      acc[nf] = __builtin_amdgcn_mfma_f32_16x16x32_bf16(af, bf, acc[nf], 0, 0, 0);
    }
  };

  // prologue: W0,X0 then W1,X1,X2,X3 -> keep newest 6, drain W0+X0
  dmaW(0); dmaX(0); dmaW(1); dmaX(1); dmaX(2); dmaX(3);
  wait_barrier<6>();

  for (int t = 0; t < 32; ++t) {
    if (t < 30) dmaW(t + 2);
    if (t < 28) dmaX(t + 4);
    compute(t);
    if (t == 0)       wait_barrier<6>();   // FIFO: [W1,X1,X2,X3,W2,X4] -> drain W1,X1
    else if (t <= 27) wait_barrier<5>();   // drain X(t+2),W(t+1); keep X(t+3),W(t+2),X(t+4)
    else if (t == 28) wait_barrier<4>();   // [X30,W29,X31,W30] -> drain X30,W29
    else if (t == 29) wait_barrier<3>();   // [X31,W30,W31] -> drain X31,W30
    else if (t == 30) wait_barrier<0>();   // drain W31
  }

  // epilogue: C row = quad*4+i, col = n (+16*nf)
#pragma unroll
  for (int nf = 0; nf < 6; ++nf) {
    const int gc = cg * 96 + nf * 16;
    const int p = gc >> 6;
    const int rcol = (gc & 63) + n;
#pragma unroll
    for (int i = 0; i < 4; ++i) {
      const int R = r0 + mg * 16 + quad * 4 + i;
      const float av = acc[nf][i];
      if (p == 0)      qo[(size_t)R * HD + rcol] = f2bf(av);
      else if (p == 1) ko[(size_t)R * HD + rcol] = f2bf(av);
      else {
        // V transposed [b][d][t'] + 32-key-group swizzle so attn PV B-frags are single 16B loads
        const int t2 = R & (TS - 1), b = t2 & 31;
        const int pos = (t2 & ~31) | (((b >> 2) & 3) << 3) | (((b >> 4) & 1) << 2) | (b & 3);
        vo[(size_t)(R >> 11) * HD * TS + (size_t)rcol * TS + pos] = (_Float16)av;
      }
    }
  }
}

// ---- kernel 2: attention. grid 512 x 256 thr (4 waves = 2 key-halves x 2 q-waves, 32 q/block).
// 32-key chunks (32 iters/half), K/V 4-buf DMA (2-ahead) = 64 KB -> 2 blocks/CU,
// steady wait<4> keeps one full chunk in flight. S^T=K Q^T; exp2; l via P*ones; f16 PV.
__global__ __launch_bounds__(256) void attn_kernel(
    const short* __restrict__ q, const short* __restrict__ k,
    const _Float16* __restrict__ vT, float* __restrict__ out)
{
  __shared__ __align__(16) char smem[65536];   // Ks[2][4][32][64]s | Vs[2][4][64][32]h
  const int tid = threadIdx.x;
  const int wv = tid >> 6, lane = tid & 63, n = lane & 15, quad = lane >> 4;
  const int half = wv >> 1, qw = wv & 1;
  const int batch = blockIdx.x & 7;            // XCD swizzle: batch K/V pinned per XCD L2
  const int qg = blockIdx.x >> 3;
  const int m0 = batch * TS + qg * 32;
  const short*    kb = k  + (size_t)batch * TS * HD;
  const _Float16* vb = vT + (size_t)batch * HD * TS;
  const f4 fz = {0.f, 0.f, 0.f, 0.f};

  auto kbuf = [&](int b) { return (short*)   (smem +         (half * 4 + b) * 4096); };
  auto vbuf = [&](int b) { return (_Float16*)(smem + 32768 + (half * 4 + b) * 4096); };

  // chunk t: keys [half*1024 + t*32, +32). 4 DMA instr/wave (2 K + 2 V).
  auto dmaKV = [&](int t) {
    const int b = t & 3;
    const int c0 = half * 1024 + t * 32;
#pragma unroll
    for (int u = 0; u < 2; ++u) {
      const int K0 = qw * 16 + u * 8;
      const int key = K0 + (lane >> 3);
      const int s = lane & 7;
      gl2lds(&kb[(size_t)(c0 + key) * HD + (((s + key) & 7) << 3)], kbuf(b) + K0 * 64);
    }
#pragma unroll
    for (int u = 0; u < 2; ++u) {
      const int D0 = qw * 32 + u * 16;
      const int d = D0 + (lane >> 2);
      const int s = lane & 3;
      const int gs = (s + d + (d >> 2)) & 3;   // +d>>2 kills 4-apart bank conflicts
      gl2lds(&vb[(size_t)d * TS + c0 + gs * 8], vbuf(b) + D0 * 32);
    }
  };

  s8v qf[2];
#pragma unroll
  for (int kc = 0; kc < 2; ++kc)
    qf[kc] = *(const s8v*)&q[(size_t)(m0 + qw * 16 + n) * HD + kc * 32 + quad * 8];

  f4 o[4] = {fz, fz, fz, fz};
  f4 lD = fz;
  h8 ones;
#pragma unroll
  for (int j = 0; j < 8; ++j) ones[j] = (_Float16)1.0f;

  dmaKV(0); dmaKV(1);
  wait_barrier<4>();                 // chunk0 landed; chunk1 in flight

  for (int t = 0; t < 32; ++t) {
    if (t < 30) dmaKV(t + 2);
    {
      const short*    ks = kbuf(t & 3);
      const _Float16* vs = vbuf(t & 3);

      s8v kf[2][2];
#pragma unroll
      for (int f = 0; f < 2; ++f)
#pragma unroll
        for (int kc = 0; kc < 2; ++kc) {
          const int key = f * 16 + n;
          kf[f][kc] = *(const s8v*)&ks[key * 64 + (((kc * 4 + quad) - key) & 7) * 8];
        }

      f4 st[2];
#pragma unroll
      for (int f = 0; f < 2; ++f) {
        st[f] = __builtin_amdgcn_mfma_f32_16x16x32_bf16(kf[f][0], qf[0], fz, 0, 0, 0);
        st[f] = __builtin_amdgcn_mfma_f32_16x16x32_bf16(kf[f][1], qf[1], st[f], 0, 0, 0);
      }

      h8 pa;
#pragma unroll
      for (int hf = 0; hf < 2; ++hf)
#pragma unroll
        for (int i = 0; i < 4; ++i)
          pa[hf * 4 + i] = (_Float16)__builtin_amdgcn_exp2f(st[hf][i]);

      lD = __builtin_amdgcn_mfma_f32_16x16x32_f16(pa, ones, lD, 0, 0, 0);
#pragma unroll
      for (int g = 0; g < 4; ++g) {
        const int d = g * 16 + n;
        const h8 vf = *(const h8*)&vs[d * 32 + ((quad - d - (d >> 2)) & 3) * 8];
        o[g] = __builtin_amdgcn_mfma_f32_16x16x32_f16(pa, vf, o[g], 0, 0, 0);
      }
    }
    if (t < 30)       wait_barrier<4>();   // chunk t+1 landed; t+2 stays in flight
    else if (t == 30) wait_barrier<0>();
  }

  __syncthreads();                   // done with K/V LDS before combine overlay

  float* o_c = (float*)smem;         // [4 waves][16 q][68]
  float* l_c = (float*)(smem + 17408);
  if (n == 0)
#pragma unroll
    for (int i = 0; i < 4; ++i) l_c[wv * 16 + quad * 4 + i] = lD[i];
#pragma unroll
  for (int g = 0; g < 4; ++g)
#pragma unroll
    for (int i = 0; i < 4; ++i)
      o_c[(wv * 16 + quad * 4 + i) * 68 + g * 16 + n] = o[g][i];
  __syncthreads();

  // combine halves: 256 thr = 32 q x 8 d-groups of 8. wave(half,qw) -> slot half*2+qw
  const int qr = tid >> 3, d8 = (tid & 7) * 8;
  const int qw2 = qr >> 4, wr = qr & 15;
  const float L = l_c[qw2 * 16 + wr] + l_c[(2 + qw2) * 16 + wr];
  const float inv = 1.0f / L;
  f4 s0 = *(const f4*)&o_c[(qw2 * 16 + wr) * 68 + d8];
  f4 s1 = *(const f4*)&o_c[(qw2 * 16 + wr) * 68 + d8 + 4];
  s0 += *(const f4*)&o_c[((2 + qw2) * 16 + wr) * 68 + d8];
  s1 += *(const f4*)&o_c[((2 + qw2) * 16 + wr) * 68 + d8 + 4];
  s0 *= inv; s1 *= inv;
  *(f4*)&out[(size_t)(m0 + qr) * HD + d8]     = s0;
  *(f4*)&out[(size_t)(m0 + qr) * HD + d8 + 4] = s1;
}

extern "C" void kernel_launch(void* const* d_in, const int* in_sizes, int n_in,
                              void* d_out, int out_size, void* d_ws, size_t ws_size,
                              hipStream_t stream) {
  const float* x  = (const float*)d_in[0];
  const float* Wk = (const float*)d_in[1];
  const float* Wq = (const float*)d_in[2];
  const float* Wv = (const float*)d_in[3];
  float* out = (float*)d_out;

  short* qb = (short*)d_ws;                           // [MTOT][64] bf16 (pre-scaled)
  short* kb = qb + (size_t)MTOT * HD;                 // [MTOT][64] bf16
  _Float16* vb = (_Float16*)(kb + (size_t)MTOT * HD); // [NB][64][TS] f16, key-swizzled
  short* wb = (short*)(vb + (size_t)NB * HD * TS);    // [192][1024] bf16 weights

  wconv_kernel<<<192, 256, 0, stream>>>(Wk, Wq, Wv, wb);
  proj_kernel<<<MTOT / 32, 256, 0, stream>>>(x, wb, qb, kb, vb);
  attn_kernel<<<MTOT / 32, 256, 0, stream>>>(qb, kb, vb, out);
}

// Round 11
// 133.102 us; speedup vs baseline: 1.0475x; 1.0475x over previous
//
#include <hip/hip_runtime.h>
#include <cstdint>

#define NB 8
#define TS 2048
#define NE 1024
#define HD 64
#define MTOT (NB*TS)

typedef float     f4  __attribute__((ext_vector_type(4)));
typedef short     s8v __attribute__((ext_vector_type(8)));
typedef short     s4v __attribute__((ext_vector_type(4)));
typedef int       i4v __attribute__((ext_vector_type(4)));
typedef _Float16  h8  __attribute__((ext_vector_type(8)));

__device__ __forceinline__ short f2bf(float f) {  // RNE
  union { float f; uint32_t u; } x; x.f = f;
  return (short)((x.u + 0x7FFFu + ((x.u >> 16) & 1u)) >> 16);
}

// pack two fp32 -> (bf16(lo) | bf16(hi)<<16) via +0x8000 round + v_perm byte select
__device__ __forceinline__ int pack2(float lo, float hi) {
  union { float f; uint32_t u; } a, b; a.f = lo; b.f = hi;
  return (int)__builtin_amdgcn_perm(b.u + 0x8000u, a.u + 0x8000u, 0x07060302u);
}

// async global->LDS DMA, 16B/lane; lptr wave-uniform, lane i -> lptr + i*16
__device__ __forceinline__ void gl2lds(const void* gptr, void* lptr) {
  auto g = (const __attribute__((address_space(1))) uint32_t*)gptr;
  auto l = (__attribute__((address_space(3))) uint32_t*)lptr;
  __builtin_amdgcn_global_load_lds(g, l, 16, 0, 0);
}

// barrier keeping the N newest vmem ops (per wave) in flight
template <int N>
__device__ __forceinline__ void wait_barrier() {
  asm volatile("s_waitcnt vmcnt(%0) lgkmcnt(0)" :: "n"(N) : "memory");
  __builtin_amdgcn_s_barrier();
}

// ---- kernel 0: W fp32 -> bf16 (q-scale folded). wb [192][1024]: 0-63 q, 64-127 k, 128-191 v
__global__ __launch_bounds__(256) void wconv_kernel(
    const float* __restrict__ Wk, const float* __restrict__ Wq, const float* __restrict__ Wv,
    short* __restrict__ wb)
{
  const int idx = (blockIdx.x * 256 + threadIdx.x) * 4;
  const int p = idx >> 16;
  const int off = idx & 65535;
  const float* W = (p == 0) ? Wq : (p == 1) ? Wk : Wv;
  const float s = (p == 0) ? 0.18033688011112042f : 1.0f; // (1/8)*log2(e)
  const float4 v = *(const float4*)&W[off];
  s4v h; h[0] = f2bf(v.x*s); h[1] = f2bf(v.y*s); h[2] = f2bf(v.z*s); h[3] = f2bf(v.w*s);
  *(s4v*)&wb[idx] = h;
}

// ---- kernel 1: fused qkv projection. grid 512 x 256 thr (4 waves), tile 32 rows x 192 cols,
// wave = 32 rows x 48 cols. ONLY x staged in LDS (6-buf fp32 DMA, 4-chunk lead, 48 KB ->
// 3 blocks/CU). W read per-wave straight from L2 into registers, prefetched 1 iter ahead and
// issued BEFORE the X DMA so the compiler's wait-for-B keeps X(t+3),X(t+4),B(t+1) in flight.
__global__ __launch_bounds__(256) void proj_kernel(
    const float* __restrict__ x, const short* __restrict__ wb,
    short* __restrict__ qo, short* __restrict__ ko, _Float16* __restrict__ vo)
{
  __shared__ float Xs[6][32][64];    // 48 KB
  const int tid = threadIdx.x;
  const int wv = tid >> 6, lane = tid & 63, n = lane & 15, quad = lane >> 4;
  const int r0 = blockIdx.x * 32;

  // X DMA: chunk = 32 rows x 64 f32 (8 KB) = 2 instr/wave. Slot swizzle (s+row)&15.
  auto dmaX = [&](int c) {
#pragma unroll
    for (int u = 0; u < 2; ++u) {
      const int R0 = (wv * 2 + u) * 4;
      const int row = R0 + (lane >> 4);
      const int s = lane & 15;
      const int gs = (s + row) & 15;
      gl2lds(&x[(size_t)(r0 + row) * NE + c * 64 + gs * 4], &Xs[c % 6][R0][0]);
    }
  };
  // B fragments for chunk c: wave's 48 cols (3 nf x 2 kc), plain global loads (L2-hot)
  auto loadB = [&](int c, s8v (*b)[2]) {
#pragma unroll
    for (int nf = 0; nf < 3; ++nf) {
      const short* wp = &wb[(size_t)(wv * 48 + nf * 16 + n) * NE + c * 64 + quad * 8];
      b[nf][0] = *(const s8v*)wp;
      b[nf][1] = *(const s8v*)(wp + 32);
    }
  };

  const f4 fz = {0.f, 0.f, 0.f, 0.f};
  f4 acc[2][3];
#pragma unroll
  for (int m = 0; m < 2; ++m)
#pragma unroll
    for (int nf = 0; nf < 3; ++nf) acc[m][nf] = fz;

  s8v bcur[3][2], bnxt[3][2];

  // prologue: B(0) first, then X0..X3. wait<6> drains B(0)+X0, keeps X1..X3 flying.
  loadB(0, bcur);
  dmaX(0); dmaX(1); dmaX(2); dmaX(3);
  wait_barrier<6>();

#pragma unroll
  for (int t = 0; t < 16; ++t) {
    if (t < 15) loadB(t + 1, bnxt);       // B first: older than this iter's X in the FIFO
    if (t < 12) dmaX(t + 4);

    // A frags from LDS chunk t (both m-tiles), fp32 -> bf16 in-reg
    const int bx = t % 6;
    s8v a[2][2];
#pragma unroll
    for (int m = 0; m < 2; ++m) {
      const int row = m * 16 + n;
      const float* pr = &Xs[bx][row][0];
#pragma unroll
      for (int kc = 0; kc < 2; ++kc) {
        const int u0 = kc * 8 + quad * 2;
        const f4 f0 = *(const f4*)(pr + (((u0    ) - row) & 15) * 4);
        const f4 f1 = *(const f4*)(pr + (((u0 + 1) - row) & 15) * 4);
        i4v ai;
        ai[0] = pack2(f0[0], f0[1]); ai[1] = pack2(f0[2], f0[3]);
        ai[2] = pack2(f1[0], f1[1]); ai[3] = pack2(f1[2], f1[3]);
        a[m][kc] = __builtin_bit_cast(s8v, ai);
      }
    }
#pragma unroll
    for (int nf = 0; nf < 3; ++nf)
#pragma unroll
      for (int m = 0; m < 2; ++m) {
        acc[m][nf] = __builtin_amdgcn_mfma_f32_16x16x32_bf16(a[m][0], bcur[nf][0], acc[m][nf], 0, 0, 0);
        acc[m][nf] = __builtin_amdgcn_mfma_f32_16x16x32_bf16(a[m][1], bcur[nf][1], acc[m][nf], 0, 0, 0);
      }
#pragma unroll
    for (int nf = 0; nf < 3; ++nf)
#pragma unroll
      for (int kc = 0; kc < 2; ++kc) bcur[nf][kc] = bnxt[nf][kc];

    // barrier: guarantee X(t+1) landed; keep newest {X(t+4), B(t+1), X(t+3)} in flight
    if (t < 12)       wait_barrier<10>();
    else if (t == 12) wait_barrier<8>();
    else if (t == 13) wait_barrier<6>();
    else if (t == 14) wait_barrier<6>();
  }

  // epilogue: C row = quad*4+i (+16m), col = wv*48 + nf*16 + n
#pragma unroll
  for (int nf = 0; nf < 3; ++nf) {
    const int base = wv * 48 + nf * 16;
    const int p = base >> 6;
    const int rcol = (base & 63) + n;
#pragma unroll
    for (int m = 0; m < 2; ++m)
#pragma unroll
      for (int i = 0; i < 4; ++i) {
        const int R = r0 + m * 16 + quad * 4 + i;
        const float av = acc[m][nf][i];
        if (p == 0)      qo[(size_t)R * HD + rcol] = f2bf(av);
        else if (p == 1) ko[(size_t)R * HD + rcol] = f2bf(av);
        else {
          // V transposed [b][d][t'] + 32-key-group swizzle so attn PV B-frags are single 16B loads
          const int t2 = R & (TS - 1), b = t2 & 31;
          const int pos = (t2 & ~31) | (((b >> 2) & 3) << 3) | (((b >> 4) & 1) << 2) | (b & 3);
          vo[(size_t)(R >> 11) * HD * TS + (size_t)rcol * TS + pos] = (_Float16)av;
        }
      }
  }
}

// ---- kernel 2: attention (r7 version — best run). grid 256 x 512 thr (8 waves). 64 q/block;
// waves 0-3 keys [0,1024), waves 4-7 keys [1024,2048). 64-key chunks, 3-buf 2-ahead DMA.
__global__ __launch_bounds__(512) void attn_kernel(
    const short* __restrict__ q, const short* __restrict__ k,
    const _Float16* __restrict__ vT, float* __restrict__ out)
{
  __shared__ __align__(16) char smem[98304];   // K[2][3][64][64]s | V[2][3][64][64]h
  const int tid = threadIdx.x;
  const int wv = tid >> 6, lane = tid & 63, n = lane & 15, quad = lane >> 4;
  const int half = wv >> 2, qw = wv & 3;
  const int batch = blockIdx.x & 7;            // XCD swizzle: batch K/V pinned per XCD L2
  const int qg = blockIdx.x >> 3;
  const int m0 = batch * TS + qg * 64;
  const short*    kb = k  + (size_t)batch * TS * HD;
  const _Float16* vb = vT + (size_t)batch * HD * TS;
  const int drow = lane >> 3, dslot = lane & 7;
  const f4 fz = {0.f, 0.f, 0.f, 0.f};

  auto kbuf = [&](int buf) { return (short*)   (smem +         (half * 3 + buf) * 8192); };
  auto vbuf = [&](int buf) { return (_Float16*)(smem + 49152 + (half * 3 + buf) * 8192); };

  auto dmaKV = [&](int tt, int buf) {
    const int c = half * 16 + tt;
#pragma unroll
    for (int u = 0; u < 2; ++u) {
      const int K0 = (qw * 2 + u) * 8;
      const int key = K0 + drow;
      const int gs = (dslot + key) & 7;
      gl2lds(&kb[(size_t)(c * 64 + key) * HD + gs * 8], kbuf(buf) + K0 * 64);
    }
#pragma unroll
    for (int u = 0; u < 2; ++u) {
      const int D0 = (qw * 2 + u) * 8;
      const int d = D0 + drow;
      const int gs = (dslot + d) & 7;
      gl2lds(&vb[(size_t)d * TS + c * 64 + gs * 8], vbuf(buf) + D0 * 64);
    }
  };

  s8v qf[2];
#pragma unroll
  for (int kc = 0; kc < 2; ++kc)
    qf[kc] = *(const s8v*)&q[(size_t)(m0 + qw * 16 + n) * HD + kc * 32 + quad * 8];

  f4 o[4] = {fz, fz, fz, fz};
  f4 lD = fz;
  h8 ones;
#pragma unroll
  for (int j = 0; j < 8; ++j) ones[j] = (_Float16)1.0f;

  dmaKV(0, 0); dmaKV(1, 1);
  wait_barrier<4>();

  for (int t = 0; t < 16; ++t) {
    const int buf = t % 3;
    if (t <= 13) dmaKV(t + 2, (t + 2) % 3);

    const short*    ks = kbuf(buf);
    const _Float16* vs = vbuf(buf);

    s8v kf[4][2];
#pragma unroll
    for (int f = 0; f < 4; ++f)
#pragma unroll
      for (int kc = 0; kc < 2; ++kc) {
        const int key = f * 16 + n;
        kf[f][kc] = *(const s8v*)&ks[key * 64 + (((kc * 4 + quad) - key) & 7) * 8];
      }

    f4 st[4];
#pragma unroll
    for (int f = 0; f < 4; ++f) {
      st[f] = __builtin_amdgcn_mfma_f32_16x16x32_bf16(kf[f][0], qf[0], fz, 0, 0, 0);
      st[f] = __builtin_amdgcn_mfma_f32_16x16x32_bf16(kf[f][1], qf[1], st[f], 0, 0, 0);
    }

    h8 pa[2];
#pragma unroll
    for (int pr = 0; pr < 2; ++pr)
#pragma unroll
      for (int hf = 0; hf < 2; ++hf)
#pragma unroll
        for (int i = 0; i < 4; ++i)
          pa[pr][hf * 4 + i] = (_Float16)__builtin_amdgcn_exp2f(st[pr * 2 + hf][i]);

#pragma unroll
    for (int pr = 0; pr < 2; ++pr) {
      lD = __builtin_amdgcn_mfma_f32_16x16x32_f16(pa[pr], ones, lD, 0, 0, 0);
#pragma unroll
      for (int g = 0; g < 4; ++g) {
        const int d = g * 16 + n;
        const h8 vf = *(const h8*)&vs[d * 64 + (((pr * 4 + quad) - d) & 7) * 8];
        o[g] = __builtin_amdgcn_mfma_f32_16x16x32_f16(pa[pr], vf, o[g], 0, 0, 0);
      }
    }

    if (t <= 13)      wait_barrier<4>();
    else if (t == 14) wait_barrier<0>();
  }

  __syncthreads();   // all waves done with K/V LDS before overlay

  float* o_c = (float*)smem;                 // [8][16][68]
  float* l_c = (float*)(smem + 36864);       // [8][16]
  if (n == 0)
#pragma unroll
    for (int i = 0; i < 4; ++i) l_c[wv * 16 + quad * 4 + i] = lD[i];
#pragma unroll
  for (int g = 0; g < 4; ++g)
#pragma unroll
    for (int i = 0; i < 4; ++i)
      o_c[(wv * 16 + quad * 4 + i) * 68 + g * 16 + n] = o[g][i];
  __syncthreads();

  // combine halves: 1024 output groups (64 q x 16 d4), 512 thr x 2 reps
#pragma unroll
  for (int rep = 0; rep < 2; ++rep) {
    const int idx = tid + rep * 512;
    const int qr = idx >> 4, d4 = (idx & 15) * 4;
    const int qw2 = qr >> 4, wr = qr & 15;
    const float L = l_c[qw2 * 16 + wr] + l_c[(qw2 + 4) * 16 + wr];
    const f4 s0 = *(const f4*)&o_c[(qw2 * 16 + wr) * 68 + d4];
    const f4 s1 = *(const f4*)&o_c[((qw2 + 4) * 16 + wr) * 68 + d4];
    f4 r = s0 + s1;
    const float inv = 1.0f / L;
    r[0] *= inv; r[1] *= inv; r[2] *= inv; r[3] *= inv;
    *(f4*)&out[(size_t)(m0 + qr) * HD + d4] = r;
  }
}

extern "C" void kernel_launch(void* const* d_in, const int* in_sizes, int n_in,
                              void* d_out, int out_size, void* d_ws, size_t ws_size,
                              hipStream_t stream) {
  const float* x  = (const float*)d_in[0];
  const float* Wk = (const float*)d_in[1];
  const float* Wq = (const float*)d_in[2];
  const float* Wv = (const float*)d_in[3];
  float* out = (float*)d_out;

  short* qb = (short*)d_ws;                           // [MTOT][64] bf16 (pre-scaled)
  short* kb = qb + (size_t)MTOT * HD;                 // [MTOT][64] bf16
  _Float16* vb = (_Float16*)(kb + (size_t)MTOT * HD); // [NB][64][TS] f16, key-swizzled
  short* wb = (short*)(vb + (size_t)NB * HD * TS);    // [192][1024] bf16 weights

  wconv_kernel<<<192, 256, 0, stream>>>(Wk, Wq, Wv, wb);
  proj_kernel<<<MTOT / 32, 256, 0, stream>>>(x, wb, qb, kb, vb);
  attn_kernel<<<MTOT / 64, 512, 0, stream>>>(qb, kb, vb, out);
}

// Round 12
// 130.670 us; speedup vs baseline: 1.0670x; 1.0186x over previous
//
#include <hip/hip_runtime.h>
#include <cstdint>

#define NB 8
#define TS 2048
#define NE 1024
#define HD 64
#define MTOT (NB*TS)

typedef float     f4  __attribute__((ext_vector_type(4)));
typedef short     s8v __attribute__((ext_vector_type(8)));
typedef short     s4v __attribute__((ext_vector_type(4)));
typedef int       i4v __attribute__((ext_vector_type(4)));
typedef _Float16  h8  __attribute__((ext_vector_type(8)));

__device__ __forceinline__ short f2bf(float f) {  // RNE
  union { float f; uint32_t u; } x; x.f = f;
  return (short)((x.u + 0x7FFFu + ((x.u >> 16) & 1u)) >> 16);
}

// pack two fp32 -> (bf16(lo) | bf16(hi)<<16) via +0x8000 round + v_perm byte select
__device__ __forceinline__ int pack2(float lo, float hi) {
  union { float f; uint32_t u; } a, b; a.f = lo; b.f = hi;
  return (int)__builtin_amdgcn_perm(b.u + 0x8000u, a.u + 0x8000u, 0x07060302u);
}

// async global->LDS DMA, 16B/lane; lptr wave-uniform, lane i -> lptr + i*16
__device__ __forceinline__ void gl2lds(const void* gptr, void* lptr) {
  auto g = (const __attribute__((address_space(1))) uint32_t*)gptr;
  auto l = (__attribute__((address_space(3))) uint32_t*)lptr;
  __builtin_amdgcn_global_load_lds(g, l, 16, 0, 0);
}

// barrier keeping the N newest vmem ops (per wave) in flight
template <int N>
__device__ __forceinline__ void wait_barrier() {
  asm volatile("s_waitcnt vmcnt(%0) lgkmcnt(0)" :: "n"(N) : "memory");
  __builtin_amdgcn_s_barrier();
}

// ---- kernel 0: W fp32 -> bf16 (q-scale folded). wb [192][1024]: 0-63 q, 64-127 k, 128-191 v
__global__ __launch_bounds__(256) void wconv_kernel(
    const float* __restrict__ Wk, const float* __restrict__ Wq, const float* __restrict__ Wv,
    short* __restrict__ wb)
{
  const int idx = (blockIdx.x * 256 + threadIdx.x) * 4;
  const int p = idx >> 16;
  const int off = idx & 65535;
  const float* W = (p == 0) ? Wq : (p == 1) ? Wk : Wv;
  const float s = (p == 0) ? 0.18033688011112042f : 1.0f; // (1/8)*log2(e)
  const float4 v = *(const float4*)&W[off];
  s4v h; h[0] = f2bf(v.x*s); h[1] = f2bf(v.y*s); h[2] = f2bf(v.z*s); h[3] = f2bf(v.w*s);
  *(s4v*)&wb[idx] = h;
}

// ---- kernel 1: fused qkv projection (exact r7 version — best run). grid 512 x 256 thr,
// tile 32 rows x 192 cols; wave = 16 rows x 96 cols. LDS 80 KB -> 2 blocks/CU.
// x: 4-buf fp32 DMA (3-ahead); W: 2-buf bf16 DMA (1-ahead). XOR slot-swizzle.
__global__ __launch_bounds__(256) void proj_kernel(
    const float* __restrict__ x, const short* __restrict__ wb,
    short* __restrict__ qo, short* __restrict__ ko, _Float16* __restrict__ vo)
{
  __shared__ float Xs[4][32][64];    // 32 KB
  __shared__ short Ws[2][192][64];   // 48 KB
  const int tid = threadIdx.x;
  const int wv = tid >> 6, lane = tid & 63, n = lane & 15, quad = lane >> 4;
  const int mg = wv & 1, cg = wv >> 1;
  const int r0 = blockIdx.x * 32;
  const int xrow = lane >> 4, xslot = lane & 15;
  const int wrow = lane >> 3, wslot = lane & 7;

  auto dmaX = [&](int c, int buf) {
#pragma unroll
    for (int u = 0; u < 2; ++u) {
      const int R0 = (wv * 2 + u) * 4;
      const int row = R0 + xrow;
      const int gs = (xslot + row) & 15;
      gl2lds(&x[(size_t)(r0 + row) * NE + c * 64 + gs * 4], &Xs[buf][R0][0]);
    }
  };
  auto dmaW = [&](int c, int buf) {
#pragma unroll
    for (int u = 0; u < 6; ++u) {
      const int C0 = (wv * 6 + u) * 8;
      const int col = C0 + wrow;
      const int gs = (wslot + col) & 7;
      gl2lds(&wb[(size_t)col * NE + c * 64 + gs * 8], &Ws[buf][C0][0]);
    }
  };

  const f4 fz = {0.f, 0.f, 0.f, 0.f};
  f4 acc[6] = {fz, fz, fz, fz, fz, fz};

  auto compute = [&](int bw, int bx) {
    s8v a[2];
    const int row = mg * 16 + n;
#pragma unroll
    for (int kc = 0; kc < 2; ++kc) {
      const int u0 = kc * 8 + quad * 2;
      const float* pr = &Xs[bx][row][0];
      const f4 f0 = *(const f4*)(pr + (((u0    ) - row) & 15) * 4);
      const f4 f1 = *(const f4*)(pr + (((u0 + 1) - row) & 15) * 4);
      i4v ai;
      ai[0] = pack2(f0[0], f0[1]); ai[1] = pack2(f0[2], f0[3]);
      ai[2] = pack2(f1[0], f1[1]); ai[3] = pack2(f1[2], f1[3]);
      a[kc] = __builtin_bit_cast(s8v, ai);
    }
#pragma unroll
    for (int nf = 0; nf < 6; ++nf) {
      const int col = cg * 96 + nf * 16 + n;
      const s8v b0 = *(const s8v*)&Ws[bw][col][(((0 + quad) - col) & 7) * 8];
      const s8v b1 = *(const s8v*)&Ws[bw][col][(((4 + quad) - col) & 7) * 8];
      acc[nf] = __builtin_amdgcn_mfma_f32_16x16x32_bf16(a[0], b0, acc[nf], 0, 0, 0);
      acc[nf] = __builtin_amdgcn_mfma_f32_16x16x32_bf16(a[1], b1, acc[nf], 0, 0, 0);
    }
  };

  dmaW(0, 0); dmaX(0, 0); dmaX(1, 1); dmaX(2, 2);
  wait_barrier<4>();

  for (int t = 0; t < 16; ++t) {
    if (t <= 14) dmaW(t + 1, (t + 1) & 1);
    if (t <= 12) dmaX(t + 3, (t + 3) & 3);
    compute(t & 1, t & 3);
    if (t <= 12)      wait_barrier<2>();
    else if (t <= 14) wait_barrier<0>();
  }

#pragma unroll
  for (int nf = 0; nf < 6; ++nf) {
    const int gc = cg * 96 + nf * 16;
    const int p = gc >> 6;
    const int rcol = (gc & 63) + n;
#pragma unroll
    for (int i = 0; i < 4; ++i) {
      const int R = r0 + mg * 16 + quad * 4 + i;
      const float av = acc[nf][i];
      if (p == 0)      qo[(size_t)R * HD + rcol] = f2bf(av);
      else if (p == 1) ko[(size_t)R * HD + rcol] = f2bf(av);
      else {
        // V transposed [b][d][t'] + 32-key-group swizzle: key p=f*16+quad*4+i -> pos quad*8+f*4+i
        const int t2 = R & (TS - 1), b = t2 & 31;
        const int pos = (t2 & ~31) | (((b >> 2) & 3) << 3) | (((b >> 4) & 1) << 2) | (b & 3);
        vo[(size_t)(R >> 11) * HD * TS + (size_t)rcol * TS + pos] = (_Float16)av;
      }
    }
  }
}

// ---- kernel 2: attention. grid 256 x 512 thr (8 waves = 4 key-quarters x 2 q-waves).
// Wave = 32 q x 512 keys in 16 chunks of 32. K/V 3-buf DMA 2-ahead (96 KB LDS).
// Per chunk: 8 b128 ds_reads for 18 MFMA (vs r7's 16) — K/V frags amortized over 2 m-tiles.
// 32-key chunk = exactly one PV A-frag (16x16x32); V swizzle pos=quad*8+f*4+i matches j=f*4+i.
__global__ __launch_bounds__(512) void attn_kernel(
    const short* __restrict__ q, const short* __restrict__ k,
    const _Float16* __restrict__ vT, float* __restrict__ out)
{
  __shared__ __align__(16) char smem[98304];   // K[4 qtr][3 buf][32][64]s | V[4][3][64][32]h
  const int tid = threadIdx.x;
  const int wv = tid >> 6, lane = tid & 63, n = lane & 15, quad = lane >> 4;
  const int qtr = wv >> 1, qw = wv & 1;
  const int batch = blockIdx.x & 7;            // XCD swizzle: batch K/V pinned per XCD L2
  const int qg = blockIdx.x >> 3;
  const int m0 = batch * TS + qg * 64;
  const short*    kb = k  + (size_t)batch * TS * HD;
  const _Float16* vb = vT + (size_t)batch * HD * TS;
  const f4 fz = {0.f, 0.f, 0.f, 0.f};

  auto kbuf = [&](int b) { return (short*)   (smem +         (qtr * 3 + b) * 4096); };
  auto vbuf = [&](int b) { return (_Float16*)(smem + 49152 + (qtr * 3 + b) * 4096); };

  // chunk t: keys [qtr*512 + t*32, +32). 4 DMA instr/wave (2 K rows-halves + 2 V d-halves).
  auto dmaKV = [&](int t) {
    const int b = t % 3;
    const int c0 = qtr * 512 + t * 32;
#pragma unroll
    for (int u = 0; u < 2; ++u) {
      const int K0 = qw * 16 + u * 8;          // K: 8 key-rows x 64 e (1 KB) per instr
      const int key = K0 + (lane >> 3);
      const int s = lane & 7;
      gl2lds(&kb[(size_t)(c0 + key) * HD + (((s + key) & 7) << 3)], kbuf(b) + K0 * 64);
    }
#pragma unroll
    for (int u = 0; u < 2; ++u) {
      const int D0 = qw * 32 + u * 16;         // V: 16 d-rows x 32 keys (1 KB) per instr
      const int d = D0 + (lane >> 2);
      const int s = lane & 3;
      gl2lds(&vb[(size_t)d * TS + c0 + (((s + d) & 3) << 3)], vbuf(b) + D0 * 32);
    }
  };

  s8v qf[2][2];
#pragma unroll
  for (int m = 0; m < 2; ++m)
#pragma unroll
    for (int kc = 0; kc < 2; ++kc)
      qf[m][kc] = *(const s8v*)&q[(size_t)(m0 + qw * 32 + m * 16 + n) * HD + kc * 32 + quad * 8];

  f4 o[2][4];
#pragma unroll
  for (int m = 0; m < 2; ++m)
#pragma unroll
    for (int g = 0; g < 4; ++g) o[m][g] = fz;
  f4 lD[2] = {fz, fz};
  h8 ones;
#pragma unroll
  for (int j = 0; j < 8; ++j) ones[j] = (_Float16)1.0f;

  dmaKV(0); dmaKV(1);
  wait_barrier<4>();                 // chunk0 landed; chunk1 in flight

  for (int t = 0; t < 16; ++t) {
    if (t <= 13) dmaKV(t + 2);
    {
      const short*    ks = kbuf(t % 3);
      const _Float16* vs = vbuf(t % 3);

      // K frags: kf[f][kc] = K[key=f*16+n][kc*32+quad*8..]
      s8v kf[2][2];
#pragma unroll
      for (int f = 0; f < 2; ++f)
#pragma unroll
        for (int kc = 0; kc < 2; ++kc) {
          const int key = f * 16 + n;
          kf[f][kc] = *(const s8v*)&ks[key * 64 + (((kc * 4 + quad) - key) & 7) * 8];
        }

      // S^T = K Q^T: C row = key = f*16 + quad*4 + i, col = q = n
      f4 st[2][2];
#pragma unroll
      for (int m = 0; m < 2; ++m)
#pragma unroll
        for (int f = 0; f < 2; ++f) {
          st[m][f] = __builtin_amdgcn_mfma_f32_16x16x32_bf16(kf[f][0], qf[m][0], fz, 0, 0, 0);
          st[m][f] = __builtin_amdgcn_mfma_f32_16x16x32_bf16(kf[f][1], qf[m][1], st[m][f], 0, 0, 0);
        }

      // P = exp2(S): A-frag slot j = f*4+i (keys f*16+quad*4+i = logical quad*8+j in V order)
      h8 pa[2];
#pragma unroll
      for (int m = 0; m < 2; ++m)
#pragma unroll
        for (int f = 0; f < 2; ++f)
#pragma unroll
          for (int i = 0; i < 4; ++i)
            pa[m][f * 4 + i] = (_Float16)__builtin_amdgcn_exp2f(st[m][f][i]);

      // V frags: one b128 per g (8 logical keys at fixed d), shared by both m-tiles
#pragma unroll
      for (int g = 0; g < 4; ++g) {
        const int d = g * 16 + n;
        const h8 vf = *(const h8*)&vs[d * 32 + ((quad - d) & 3) * 8];
        o[0][g] = __builtin_amdgcn_mfma_f32_16x16x32_f16(pa[0], vf, o[0][g], 0, 0, 0);
        o[1][g] = __builtin_amdgcn_mfma_f32_16x16x32_f16(pa[1], vf, o[1][g], 0, 0, 0);
      }
      lD[0] = __builtin_amdgcn_mfma_f32_16x16x32_f16(pa[0], ones, lD[0], 0, 0, 0);
      lD[1] = __builtin_amdgcn_mfma_f32_16x16x32_f16(pa[1], ones, lD[1], 0, 0, 0);
    }
    if (t <= 13)      wait_barrier<4>();   // chunk t+1 landed; t+2 stays in flight
    else if (t == 14) wait_barrier<0>();
  }

  __syncthreads();   // all waves done with K/V LDS before overlay

  float* o_c = (float*)smem;                 // [8 waves][32 q][68]
  float* l_c = (float*)(smem + 69632);       // [8][32]
  if (n == 0)
#pragma unroll
    for (int m = 0; m < 2; ++m)
#pragma unroll
      for (int i = 0; i < 4; ++i)
        l_c[wv * 32 + m * 16 + quad * 4 + i] = lD[m][i];
#pragma unroll
  for (int m = 0; m < 2; ++m)
#pragma unroll
    for (int g = 0; g < 4; ++g)
#pragma unroll
      for (int i = 0; i < 4; ++i)
        o_c[(wv * 32 + m * 16 + quad * 4 + i) * 68 + g * 16 + n] = o[m][g][i];
  __syncthreads();

  // combine 4 quarters: 512 thr = 64 q x 8 d-groups of 8. q row -> wave qtr*2 + (qr>>5)
  const int qr = tid >> 3, d8 = (tid & 7) * 8;
  const int qw2 = qr >> 5, r32 = qr & 31;
  float L = 0.f;
  f4 s0 = fz, s1 = fz;
#pragma unroll
  for (int qt = 0; qt < 4; ++qt) {
    const int w = qt * 2 + qw2;
    L  += l_c[w * 32 + r32];
    s0 += *(const f4*)&o_c[(w * 32 + r32) * 68 + d8];
    s1 += *(const f4*)&o_c[(w * 32 + r32) * 68 + d8 + 4];
  }
  const float inv = 1.0f / L;
  s0 *= inv; s1 *= inv;
  *(f4*)&out[(size_t)(m0 + qr) * HD + d8]     = s0;
  *(f4*)&out[(size_t)(m0 + qr) * HD + d8 + 4] = s1;
}

extern "C" void kernel_launch(void* const* d_in, const int* in_sizes, int n_in,
                              void* d_out, int out_size, void* d_ws, size_t ws_size,
                              hipStream_t stream) {
  const float* x  = (const float*)d_in[0];
  const float* Wk = (const float*)d_in[1];
  const float* Wq = (const float*)d_in[2];
  const float* Wv = (const float*)d_in[3];
  float* out = (float*)d_out;

  short* qb = (short*)d_ws;                           // [MTOT][64] bf16 (pre-scaled)
  short* kb = qb + (size_t)MTOT * HD;                 // [MTOT][64] bf16
  _Float16* vb = (_Float16*)(kb + (size_t)MTOT * HD); // [NB][64][TS] f16, key-swizzled
  short* wb = (short*)(vb + (size_t)NB * HD * TS);    // [192][1024] bf16 weights

  wconv_kernel<<<192, 256, 0, stream>>>(Wk, Wq, Wv, wb);
  proj_kernel<<<MTOT / 32, 256, 0, stream>>>(x, wb, qb, kb, vb);
  attn_kernel<<<MTOT / 64, 512, 0, stream>>>(qb, kb, vb, out);
}